// Round 3
// baseline (164.504 us; speedup 1.0000x reference)
//
#include <hip/hip_runtime.h>
#include <hip/hip_bf16.h>

#define NN 8192
#define DD 128
#define NCH 16               // column chunks per row-strip
#define CCOLS (NN / NCH)     // 512 cols per block
#define NTILE (CCOLS / 64)   // 8 tiles of 64 cols

typedef short short8 __attribute__((ext_vector_type(8)));
typedef __bf16 bf16x8 __attribute__((ext_vector_type(8)));
typedef float f32x4 __attribute__((ext_vector_type(4)));

// ---------------- prep: normalize rows, write bf16 f ----------------
__global__ __launch_bounds__(256) void prep_kernel(const float* __restrict__ x,
                                                   __hip_bfloat16* __restrict__ fb) {
  int wave = threadIdx.x >> 6;
  int lane = threadIdx.x & 63;
  int row = blockIdx.x * 4 + wave;
  const float2 v = *(const float2*)(x + (size_t)row * DD + lane * 2);
  float ss = v.x * v.x + v.y * v.y;
  for (int off = 32; off; off >>= 1) ss += __shfl_xor(ss, off, 64);
  float nrm = fmaxf(sqrtf(ss), 1e-12f);
  float fx = v.x / nrm, fy = v.y / nrm;
  __hip_bfloat162 h;
  h.x = __float2bfloat16(fx);
  h.y = __float2bfloat16(fy);
  *(__hip_bfloat162*)(fb + (size_t)row * DD + lane * 2) = h;
}

// ---------------- fused Gram + hyperbolic distance + masked row sums ----------------
// unit-norm simplification: x2=y2=1 =>
//   d  = 1 + c^2 - 2cs          (the Mobius denominator)
//   q  = nd^2 = 2c(1-s)/d
//   1-q = (1-c)^2/d  exactly => rr = (1+nd)/(1-nd) = (1+nd)^2 * d / (1-c)^2
//   adc = -dist/T = KL*log2(rr);  e = exp(adc) = exp2(KE*log2(rr))
__global__ __launch_bounds__(256, 6) void fused_kernel(
    const __hip_bfloat16* __restrict__ fbg,
    const int* __restrict__ plab, const int* __restrict__ slab,
    float* __restrict__ totg, float* __restrict__ tposg) {
  // B tile: 64 rows x 128 bf16, stored as 16B units, XOR-swizzled:
  // unit index = row*16 + (u ^ (row & 15))
  __shared__ short Bbuf[64 * 128];
  __shared__ int plc[CCOLS], slc[CCOLS];

  const int tid = threadIdx.x;
  const int w = tid >> 6;
  const int lane = tid & 63;
  const int lrow = lane & 15;
  const int quad = lane >> 4;
  const int R0 = blockIdx.y * 64;
  const int C0 = blockIdx.x * CCOLS;

  const float MK = -0.110803324099723f;   // -2c/(1-c)^2
  const float PK = 0.110803324099723f;    // +2c/(1-c)^2
  const float C1K = 1.110803324099723f;   // (1+c^2)/(1-c)^2
  const float KE = -8.944271909999159f;   // -1/(sqrt_c*T)
  const float KL = -6.199696797323639f;   // KE*ln2

  // chunk labels once
  for (int i = tid; i < CCOLS; i += 256) {
    plc[i] = plab[C0 + i];
    slc[i] = slab[C0 + i];
  }

  // A fragments: loop-invariant, load straight from global into registers.
  // af[kk][j] = f[rowA][kk*32 + quad*8 + j]
  const int rowA = R0 + w * 16 + lrow;
  bf16x8 af[4];
  {
    const short* fa = (const short*)fbg + (size_t)rowA * DD;
    for (int kk = 0; kk < 4; kk++)
      af[kk] = __builtin_bit_cast(bf16x8, *(const short8*)(fa + kk * 32 + quad * 8));
  }

  // row-side constants
  float tot[4] = {0.f, 0.f, 0.f, 0.f};
  float tps[4] = {0.f, 0.f, 0.f, 0.f};
  int rowg[4], plr[4], slr[4];
  for (int r = 0; r < 4; r++) {
    rowg[r] = R0 + w * 16 + quad * 4 + r;
    plr[r] = plab[rowg[r]];
    slr[r] = slab[rowg[r]];
  }

  for (int tile = 0; tile < NTILE; tile++) {
    const int CT = C0 + tile * 64;
    __syncthreads();  // previous tile's readers done before overwriting Bbuf
    {
      const short* gb = (const short*)fbg + (size_t)CT * DD;
      for (int i = 0; i < 4; i++) {
        int o = tid + i * 256;  // row-major 16B-unit index
        int row = o >> 4, uu = o & 15;
        int u = (row << 4) + (uu ^ (row & 15));
        *(short8*)(Bbuf + u * 8) = *(const short8*)(gb + o * 8);
      }
    }
    __syncthreads();

    const int lb = tile * 64;
    for (int ct = 0; ct < 4; ct++) {
      const int rt = ct * 16 + lrow;
      f32x4 acc = {0.f, 0.f, 0.f, 0.f};
      for (int kk = 0; kk < 4; kk++) {
        int u = (rt << 4) + ((kk * 4 + quad) ^ lrow);
        short8 t = *(const short8*)(Bbuf + u * 8);
        acc = __builtin_amdgcn_mfma_f32_16x16x32_bf16(af[kk], __builtin_bit_cast(bf16x8, t), acc, 0, 0, 0);
      }
      const int colg = CT + rt;
      const int pc = plc[lb + rt];
      const int sc = slc[lb + rt];
      for (int r = 0; r < 4; r++) {
        float s = acc[r];
        float tK = fmaf(s, MK, PK);            // 2cK*(1-s), K=1/(1-c)^2
        tK = fmaxf(tK, 0.0f);                  // bf16 noise on diagonal
        float dk = fmaf(s, MK, C1K);           // d*K
        float q = tK * __builtin_amdgcn_rcpf(dk);
        float nd = __builtin_amdgcn_sqrtf(q);  // q <= 0.19, no clip needed
        float p1 = 1.0f + nd;
        float rr = p1 * p1 * dk;               // (1+nd)^2 * d/(1-c)^2
        float lg = __log2f(rr);
        float adc = KL * lg;                   // -distance/T
        float e = exp2f(KE * lg);              // exp(adc)
        bool same = (pc == plr[r]) || (sc == slr[r]);
        bool offd = (colg != rowg[r]);
        tot[r] += offd ? e : 0.0f;
        tps[r] += (same && offd) ? adc : 0.0f;
      }
    }
  }

  // reduce across the 16 lanes sharing each output row, then atomics
  for (int r = 0; r < 4; r++) {
    float t = tot[r], tp = tps[r];
    for (int off = 1; off < 16; off <<= 1) {
      t += __shfl_xor(t, off, 16);
      tp += __shfl_xor(tp, off, 16);
    }
    if (lrow == 0) {
      atomicAdd(&totg[rowg[r]], t);
      atomicAdd(&tposg[rowg[r]], tp);
    }
  }
}

// ---------------- finalize: label histograms -> num_pos, per-row loss, reduce ----------------
__global__ __launch_bounds__(1024) void finalize_k(const float* __restrict__ totg,
                                                   const float* __restrict__ tposg,
                                                   const int* __restrict__ plab,
                                                   const int* __restrict__ slab,
                                                   float* __restrict__ out) {
  __shared__ int cntPS[512];
  __shared__ int cntP[32], cntS[16];
  __shared__ float redP[16], redV[16];
  const int tid = threadIdx.x;
  if (tid < 512) cntPS[tid] = 0;
  __syncthreads();
  for (int i = tid; i < NN; i += 1024)
    atomicAdd(&cntPS[plab[i] * 16 + slab[i]], 1);
  __syncthreads();
  if (tid < 32) {
    int s = 0;
    for (int j = 0; j < 16; j++) s += cntPS[tid * 16 + j];
    cntP[tid] = s;
  }
  if (tid < 16) {
    int s = 0;
    for (int j = 0; j < 32; j++) s += cntPS[j * 16 + tid];
    cntS[tid] = s;
  }
  __syncthreads();
  float accP = 0.f, accV = 0.f;
  for (int i = tid; i < NN; i += 1024) {
    int pl = plab[i], sl = slab[i];
    int np = cntP[pl] + cntS[sl] - cntPS[pl * 16 + sl] - 1;
    if (np > 0) {
      accP += tposg[i] / (float)np - __logf(totg[i] + 1e-8f);
      accV += 1.f;
    }
  }
  for (int off = 32; off; off >>= 1) {
    accP += __shfl_xor(accP, off, 64);
    accV += __shfl_xor(accV, off, 64);
  }
  int wv = tid >> 6;
  if ((tid & 63) == 0) { redP[wv] = accP; redV[wv] = accV; }
  __syncthreads();
  if (tid == 0) {
    float sp = 0.f, sv = 0.f;
    for (int j = 0; j < 16; j++) { sp += redP[j]; sv += redV[j]; }
    float loss = -(sp / fmaxf(sv, 1.0f)) * 0.5f;  // * TEMPERATURE
    if (sv <= 0.0f || !__builtin_isfinite(loss)) loss = 0.0f;
    out[0] = loss;
  }
}

extern "C" void kernel_launch(void* const* d_in, const int* in_sizes, int n_in,
                              void* d_out, int out_size, void* d_ws, size_t ws_size,
                              hipStream_t stream) {
  const float* x = (const float*)d_in[0];
  const int* pl = (const int*)d_in[1];
  const int* sl = (const int*)d_in[2];
  char* ws = (char*)d_ws;
  __hip_bfloat16* fb = (__hip_bfloat16*)ws;    // 2,097,152 B
  float* totg = (float*)(ws + 2097152);        // 32 KB
  float* tposg = (float*)(ws + 2129920);       // 32 KB

  (void)hipMemsetAsync(totg, 0, 65536, stream);

  prep_kernel<<<NN / 4, 256, 0, stream>>>(x, fb);
  fused_kernel<<<dim3(NCH, NN / 64), 256, 0, stream>>>(fb, pl, sl, totg, tposg);
  finalize_k<<<1, 1024, 0, stream>>>(totg, tposg, pl, sl, (float*)d_out);
}

// Round 5
// 156.806 us; speedup vs baseline: 1.0491x; 1.0491x over previous
//
#include <hip/hip_runtime.h>
#include <hip/hip_bf16.h>

#define NN 8192
#define DD 128

typedef short short8 __attribute__((ext_vector_type(8)));
typedef __bf16 bf16x8 __attribute__((ext_vector_type(8)));
typedef float f32x4 __attribute__((ext_vector_type(4)));

// unit-norm simplification (x2=y2=1):
//   d = 1 + c^2 - 2cs ;  q = nd^2 = 2c(1-s)/d ;  1-q = (1-c)^2/d exactly
//   rr = (1+nd)/(1-nd) = (1+nd)^2 * d/(1-c)^2
//   adc = -dist/T = KL*log2(rr) ; e = exp(adc) = exp2(KE*log2(rr))
#define MKc (-0.110803324099723f)   // -2c/(1-c)^2
#define PKc (0.110803324099723f)    // +2c/(1-c)^2
#define C1Kc (1.110803324099723f)   // (1+c^2)/(1-c)^2
#define KEc (-8.944271909999159f)   // -1/(sqrt_c*T)
#define KLc (-6.199696797323639f)   // KE*ln2

// ---------------- prep: normalize 16 rows/block, write bf16 ----------------
__global__ __launch_bounds__(256) void prep_kernel(const float* __restrict__ x,
                                                   __hip_bfloat16* __restrict__ fb) {
  int r = threadIdx.x >> 4, sub = threadIdx.x & 15;
  int row = blockIdx.x * 16 + r;
  const float4 a = *(const float4*)(x + (size_t)row * DD + sub * 8);
  const float4 b = *(const float4*)(x + (size_t)row * DD + sub * 8 + 4);
  float ss = a.x * a.x + a.y * a.y + a.z * a.z + a.w * a.w +
             b.x * b.x + b.y * b.y + b.z * b.z + b.w * b.w;
  for (int off = 1; off < 16; off <<= 1) ss += __shfl_xor(ss, off, 16);
  float inv = 1.0f / fmaxf(sqrtf(ss), 1e-12f);
  float va[8] = {a.x, a.y, a.z, a.w, b.x, b.y, b.z, b.w};
  short8 h;
  for (int j = 0; j < 8; j++) {
    __hip_bfloat16 t = __float2bfloat16(va[j] * inv);
    h[j] = __builtin_bit_cast(short, t);
  }
  *(short8*)((short*)fb + (size_t)row * DD + sub * 8) = h;
}

// ---------------- fused: 256 rows x 512 cols per block ----------------
__global__ __launch_bounds__(256, 2) void fused256_kernel(
    const __hip_bfloat16* __restrict__ fbg,
    const int* __restrict__ plab, const int* __restrict__ slab,
    float2* __restrict__ totlgP) {
  __shared__ short Bbuf[64 * 128];    // 16 KB, XOR-swizzled B tile
  __shared__ int plc[512], slc[512];  // 4 KB

  const int tid = threadIdx.x;
  const int w = tid >> 6;
  const int lane = tid & 63;
  const int lrow = lane & 15;
  const int quad = lane >> 4;
  const int chunk = blockIdx.x;       // 0..15
  const int R0 = blockIdx.y * 256;    // 0..31
  const int C0 = chunk * 512;

  for (int i = tid; i < 512; i += 256) {
    plc[i] = plab[C0 + i];
    slc[i] = slab[C0 + i];
  }

  // A fragments + row labels (wave w owns rows R0 + w*64 .. +63, 4 strips of 16)
  bf16x8 af[4][4];
  int plr[4][4], slr[4][4];
  for (int strip = 0; strip < 4; strip++) {
    const short* fa = (const short*)fbg + (size_t)(R0 + w * 64 + strip * 16 + lrow) * DD;
    for (int kk = 0; kk < 4; kk++)
      af[strip][kk] = __builtin_bit_cast(bf16x8, *(const short8*)(fa + kk * 32 + quad * 8));
    for (int r = 0; r < 4; r++) {
      int rowg = R0 + w * 64 + strip * 16 + quad * 4 + r;
      plr[strip][r] = plab[rowg];
      slr[strip][r] = slab[rowg];
    }
  }

  float tot[4][4], lgs[4][4];
  for (int s_ = 0; s_ < 4; s_++)
    for (int r = 0; r < 4; r++) { tot[s_][r] = 0.f; lgs[s_][r] = 0.f; }

  for (int tile = 0; tile < 8; tile++) {
    const int CT = C0 + tile * 64;
    __syncthreads();  // previous tile's readers done before overwriting Bbuf
    {
      const short* gb = (const short*)fbg + (size_t)CT * DD;
      for (int i = 0; i < 4; i++) {
        int o = tid + i * 256;  // row-major 16B-unit index
        int row = o >> 4, uu = o & 15;
        int u = (row << 4) + (uu ^ (row & 15));
        *(short8*)(Bbuf + u * 8) = *(const short8*)(gb + o * 8);
      }
    }
    __syncthreads();

    const int lb = tile * 64;
    for (int ct = 0; ct < 4; ct++) {
      const int rt = ct * 16 + lrow;
      bf16x8 bf[4];
      for (int kk = 0; kk < 4; kk++) {
        int u = (rt << 4) + ((kk * 4 + quad) ^ lrow);
        bf[kk] = __builtin_bit_cast(bf16x8, *(const short8*)(Bbuf + u * 8));
      }
      f32x4 acc[4];
      for (int strip = 0; strip < 4; strip++) {
        f32x4 a0 = {0.f, 0.f, 0.f, 0.f};
        for (int kk = 0; kk < 4; kk++)
          a0 = __builtin_amdgcn_mfma_f32_16x16x32_bf16(af[strip][kk], bf[kk], a0, 0, 0, 0);
        acc[strip] = a0;
      }
      const int colg = CT + rt;
      const int pc = plc[lb + rt];
      const int sc = slc[lb + rt];
      for (int strip = 0; strip < 4; strip++) {
        for (int r = 0; r < 4; r++) {
          float s = acc[strip][r];
          float tK = fmaxf(fmaf(s, MKc, PKc), 0.0f);  // 2cK*(1-s), clamped (diag noise)
          float dk = fmaf(s, MKc, C1Kc);              // d*K
          float m = fmaxf(tK * dk, 1e-30f);
          float nd = tK * __builtin_amdgcn_rsqf(m);   // sqrt(tK/dk), 0-safe
          float p1 = 1.0f + nd;
          float rr = p1 * p1 * dk;
          float lg = __log2f(rr);
          float e = exp2f(KEc * lg);
          int rowg = R0 + w * 64 + strip * 16 + quad * 4 + r;
          bool offd = (colg != rowg);
          bool same = (pc == plr[strip][r]) || (sc == slr[strip][r]);
          tot[strip][r] += offd ? e : 0.0f;
          lgs[strip][r] += (same && offd) ? lg : 0.0f;
        }
      }
    }
  }

  // 16-lane (column) reduce, store per-(row,chunk) partials (no atomics)
  for (int strip = 0; strip < 4; strip++) {
    for (int r = 0; r < 4; r++) {
      float t = tot[strip][r], g = lgs[strip][r];
      for (int off = 1; off < 16; off <<= 1) {
        t += __shfl_xor(t, off, 16);
        g += __shfl_xor(g, off, 16);
      }
      if (lrow == 0) {
        int rowg = R0 + w * 64 + strip * 16 + quad * 4 + r;
        totlgP[rowg * 16 + chunk] = make_float2(t, g);
      }
    }
  }
}

// ---------------- finalize: histogram -> num_pos, per-row loss, reduce ----------------
__global__ __launch_bounds__(1024) void finalize_k(const float2* __restrict__ totlgP,
                                                   const int* __restrict__ plab,
                                                   const int* __restrict__ slab,
                                                   float* __restrict__ out) {
  __shared__ int hist[512];
  __shared__ int cntP[32], cntS[16];
  __shared__ float redP[16], redV[16];
  const int tid = threadIdx.x;
  if (tid < 512) hist[tid] = 0;
  __syncthreads();
  for (int i = tid; i < NN; i += 1024)
    atomicAdd(&hist[plab[i] * 16 + slab[i]], 1);
  __syncthreads();
  if (tid < 32) {
    int s = 0;
    for (int j = 0; j < 16; j++) s += hist[tid * 16 + j];
    cntP[tid] = s;
  } else if (tid >= 64 && tid < 80) {
    int s = 0;
    for (int j = 0; j < 32; j++) s += hist[j * 16 + (tid - 64)];
    cntS[tid - 64] = s;
  }
  __syncthreads();
  float accP = 0.f, accV = 0.f;
  for (int i = tid; i < NN; i += 1024) {
    float tt = 0.f, gg = 0.f;
    const float2* p = totlgP + (size_t)i * 16;
    for (int j = 0; j < 16; j++) {
      float2 v = p[j];
      tt += v.x;
      gg += v.y;
    }
    int pl = plab[i], sl = slab[i];
    int np = cntP[pl] + cntS[sl] - hist[pl * 16 + sl] - 1;
    if (np > 0) {
      accP += (KLc * gg) / (float)np - __logf(tt + 1e-8f);
      accV += 1.f;
    }
  }
  for (int off = 32; off; off >>= 1) {
    accP += __shfl_xor(accP, off, 64);
    accV += __shfl_xor(accV, off, 64);
  }
  int wv = tid >> 6;
  if ((tid & 63) == 0) { redP[wv] = accP; redV[wv] = accV; }
  __syncthreads();
  if (tid == 0) {
    float sp = 0.f, sv = 0.f;
    for (int j = 0; j < 16; j++) { sp += redP[j]; sv += redV[j]; }
    float loss = -(sp / fmaxf(sv, 1.0f)) * 0.5f;  // * TEMPERATURE
    if (sv <= 0.0f || !__builtin_isfinite(loss)) loss = 0.0f;
    out[0] = loss;
  }
}

extern "C" void kernel_launch(void* const* d_in, const int* in_sizes, int n_in,
                              void* d_out, int out_size, void* d_ws, size_t ws_size,
                              hipStream_t stream) {
  const float* x = (const float*)d_in[0];
  const int* pl = (const int*)d_in[1];
  const int* sl = (const int*)d_in[2];
  char* ws = (char*)d_ws;
  __hip_bfloat16* fb = (__hip_bfloat16*)ws;    // 2,097,152 B
  float2* totlg = (float2*)(ws + 2097152);     // 8192*16*8 = 1,048,576 B

  prep_kernel<<<NN / 16, 256, 0, stream>>>(x, fb);
  fused256_kernel<<<dim3(16, 32), 256, 0, stream>>>(fb, pl, sl, totlg);
  finalize_k<<<1, 1024, 0, stream>>>(totlg, pl, sl, (float*)d_out);
}

// Round 6
// 145.716 us; speedup vs baseline: 1.1289x; 1.0761x over previous
//
#include <hip/hip_runtime.h>
#include <hip/hip_bf16.h>

#define NN 8192
#define DD 128

typedef short short8 __attribute__((ext_vector_type(8)));
typedef __bf16 bf16x8 __attribute__((ext_vector_type(8)));
typedef float f32x4 __attribute__((ext_vector_type(4)));

// unit-norm simplification (x2=y2=1):
//   d = 1 + c^2 - 2cs ;  q = nd^2 = 2c(1-s)/d ;  1-q = (1-c)^2/d exactly
//   rr = (1+nd)/(1-nd) = (1+nd)^2 * d/(1-c)^2
//   adc = -dist/T = KL*log2(rr) ; e = exp(adc) = exp2(KE*log2(rr))
#define MKc (-0.110803324099723f)   // -2c/(1-c)^2
#define PKc (0.110803324099723f)    // +2c/(1-c)^2
#define C1Kc (1.110803324099723f)   // (1+c^2)/(1-c)^2
#define KEc (-8.944271909999159f)   // -1/(sqrt_c*T)
#define KLc (-6.199696797323639f)   // KE*ln2

// ---------------- prep: normalize 16 rows/block, write bf16 ----------------
__global__ __launch_bounds__(256) void prep_kernel(const float* __restrict__ x,
                                                   __hip_bfloat16* __restrict__ fb) {
  int r = threadIdx.x >> 4, sub = threadIdx.x & 15;
  int row = blockIdx.x * 16 + r;
  const float4 a = *(const float4*)(x + (size_t)row * DD + sub * 8);
  const float4 b = *(const float4*)(x + (size_t)row * DD + sub * 8 + 4);
  float ss = a.x * a.x + a.y * a.y + a.z * a.z + a.w * a.w +
             b.x * b.x + b.y * b.y + b.z * b.z + b.w * b.w;
  for (int off = 1; off < 16; off <<= 1) ss += __shfl_xor(ss, off, 16);
  float inv = 1.0f / fmaxf(sqrtf(ss), 1e-12f);
  float va[8] = {a.x, a.y, a.z, a.w, b.x, b.y, b.z, b.w};
  short8 h;
  for (int j = 0; j < 8; j++) {
    __hip_bfloat16 t = __float2bfloat16(va[j] * inv);
    h[j] = __builtin_bit_cast(short, t);
  }
  *(short8*)((short*)fb + (size_t)row * DD + sub * 8) = h;
}

// ---------------- fused: 128 rows x 512 cols per block, 4 blocks/CU ----------------
__global__ __launch_bounds__(256, 4) void fused128_kernel(
    const __hip_bfloat16* __restrict__ fbg,
    const int* __restrict__ plab, const int* __restrict__ slab,
    float* __restrict__ totg, float* __restrict__ tposg) {
  __shared__ short Bbuf[64 * 128];    // 16 KB, XOR-swizzled B tile
  __shared__ int plc[512], slc[512];  // 4 KB

  const int tid = threadIdx.x;
  const int w = tid >> 6;
  const int lane = tid & 63;
  const int lrow = lane & 15;
  const int quad = lane >> 4;
  const int chunk = blockIdx.x;       // 0..15
  const int R0 = blockIdx.y * 128;    // 0..63
  const int C0 = chunk * 512;

  for (int i = tid; i < 512; i += 256) {
    plc[i] = plab[C0 + i];
    slc[i] = slab[C0 + i];
  }

  // A fragments + row labels (wave w owns rows R0 + w*32 .. +31, 2 strips of 16)
  bf16x8 af[2][4];
  int plr[2][4], slr[2][4];
  for (int strip = 0; strip < 2; strip++) {
    const short* fa = (const short*)fbg + (size_t)(R0 + w * 32 + strip * 16 + lrow) * DD;
    for (int kk = 0; kk < 4; kk++)
      af[strip][kk] = __builtin_bit_cast(bf16x8, *(const short8*)(fa + kk * 32 + quad * 8));
    for (int r = 0; r < 4; r++) {
      int rowg = R0 + w * 32 + strip * 16 + quad * 4 + r;
      plr[strip][r] = plab[rowg];
      slr[strip][r] = slab[rowg];
    }
  }

  float tot[2][4], lgs[2][4];
  for (int s_ = 0; s_ < 2; s_++)
    for (int r = 0; r < 4; r++) { tot[s_][r] = 0.f; lgs[s_][r] = 0.f; }

  for (int tile = 0; tile < 8; tile++) {
    const int CT = C0 + tile * 64;
    __syncthreads();  // previous tile's readers done before overwriting Bbuf
    {
      const short* gb = (const short*)fbg + (size_t)CT * DD;
      for (int i = 0; i < 4; i++) {
        int o = tid + i * 256;  // row-major 16B-unit index
        int row = o >> 4, uu = o & 15;
        int u = (row << 4) + (uu ^ (row & 15));
        *(short8*)(Bbuf + u * 8) = *(const short8*)(gb + o * 8);
      }
    }
    __syncthreads();

    const int lb = tile * 64;
    for (int ct = 0; ct < 4; ct++) {
      const int rt = ct * 16 + lrow;
      bf16x8 bf[4];
      for (int kk = 0; kk < 4; kk++) {
        int u = (rt << 4) + ((kk * 4 + quad) ^ lrow);
        bf[kk] = __builtin_bit_cast(bf16x8, *(const short8*)(Bbuf + u * 8));
      }
      f32x4 acc[2];
      for (int strip = 0; strip < 2; strip++) {
        f32x4 a0 = {0.f, 0.f, 0.f, 0.f};
        for (int kk = 0; kk < 4; kk++)
          a0 = __builtin_amdgcn_mfma_f32_16x16x32_bf16(af[strip][kk], bf[kk], a0, 0, 0, 0);
        acc[strip] = a0;
      }
      const int colg = CT + rt;
      const int pc = plc[lb + rt];
      const int sc = slc[lb + rt];
      for (int strip = 0; strip < 2; strip++) {
        for (int r = 0; r < 4; r++) {
          float s = acc[strip][r];
          float tK = fmaxf(fmaf(s, MKc, PKc), 0.0f);  // 2cK*(1-s), clamped (diag noise)
          float dk = fmaf(s, MKc, C1Kc);              // d*K
          float m = fmaxf(tK * dk, 1e-30f);
          float nd = tK * __builtin_amdgcn_rsqf(m);   // sqrt(tK/dk), 0-safe
          float p1 = 1.0f + nd;
          float rr = p1 * p1 * dk;
          float lg = __log2f(rr);
          float e = exp2f(KEc * lg);
          int rowg = R0 + w * 32 + strip * 16 + quad * 4 + r;
          bool offd = (colg != rowg);
          bool same = (pc == plr[strip][r]) || (sc == slr[strip][r]);
          tot[strip][r] += offd ? e : 0.0f;
          lgs[strip][r] += (same && offd) ? lg : 0.0f;
        }
      }
    }
  }

  // 16-lane (column) reduce, then per-row atomic partials (zeroed by memset node)
  for (int strip = 0; strip < 2; strip++) {
    for (int r = 0; r < 4; r++) {
      float t = tot[strip][r], g = lgs[strip][r];
      for (int off = 1; off < 16; off <<= 1) {
        t += __shfl_xor(t, off, 16);
        g += __shfl_xor(g, off, 16);
      }
      if (lrow == 0) {
        int rowg = R0 + w * 32 + strip * 16 + quad * 4 + r;
        atomicAdd(&totg[rowg], t);
        atomicAdd(&tposg[rowg], g);
      }
    }
  }
}

// ---------------- finalize stage 1: 32 blocks, 1 row/thread ----------------
__global__ __launch_bounds__(256) void final1_k(const float* __restrict__ totg,
                                                const float* __restrict__ tposg,
                                                const int* __restrict__ plab,
                                                const int* __restrict__ slab,
                                                float* __restrict__ scal) {
  __shared__ int hist[512];
  __shared__ int cntP[32], cntS[16];
  __shared__ float redP[4], redV[4];
  const int tid = threadIdx.x;
  for (int i = tid; i < 512; i += 256) hist[i] = 0;
  __syncthreads();
  for (int i = tid; i < NN; i += 256)
    atomicAdd(&hist[plab[i] * 16 + slab[i]], 1);
  __syncthreads();
  if (tid < 32) {
    int s = 0;
    for (int j = 0; j < 16; j++) s += hist[tid * 16 + j];
    cntP[tid] = s;
  } else if (tid >= 64 && tid < 80) {
    int s = 0;
    for (int j = 0; j < 32; j++) s += hist[j * 16 + (tid - 64)];
    cntS[tid - 64] = s;
  }
  __syncthreads();
  const int i = blockIdx.x * 256 + tid;
  const int pl = plab[i], sl = slab[i];
  const int np = cntP[pl] + cntS[sl] - hist[pl * 16 + sl] - 1;
  float accP = 0.f, accV = 0.f;
  if (np > 0) {
    accP = (KLc * tposg[i]) / (float)np - __logf(totg[i] + 1e-8f);
    accV = 1.f;
  }
  for (int off = 32; off; off >>= 1) {
    accP += __shfl_xor(accP, off, 64);
    accV += __shfl_xor(accV, off, 64);
  }
  int wv = tid >> 6;
  if ((tid & 63) == 0) { redP[wv] = accP; redV[wv] = accV; }
  __syncthreads();
  if (tid == 0) {
    atomicAdd(&scal[0], redP[0] + redP[1] + redP[2] + redP[3]);
    atomicAdd(&scal[1], redV[0] + redV[1] + redV[2] + redV[3]);
  }
}

// ---------------- finalize stage 2 ----------------
__global__ void final2_k(const float* __restrict__ scal, float* __restrict__ out) {
  float sp = scal[0], sv = scal[1];
  float loss = -(sp / fmaxf(sv, 1.0f)) * 0.5f;  // * TEMPERATURE
  if (sv <= 0.0f || !__builtin_isfinite(loss)) loss = 0.0f;
  out[0] = loss;
}

extern "C" void kernel_launch(void* const* d_in, const int* in_sizes, int n_in,
                              void* d_out, int out_size, void* d_ws, size_t ws_size,
                              hipStream_t stream) {
  const float* x = (const float*)d_in[0];
  const int* pl = (const int*)d_in[1];
  const int* sl = (const int*)d_in[2];
  char* ws = (char*)d_ws;
  __hip_bfloat16* fb = (__hip_bfloat16*)ws;    // 2,097,152 B
  float* totg = (float*)(ws + 2097152);        // 32 KB
  float* tposg = (float*)(ws + 2129920);       // 32 KB
  float* scal = (float*)(ws + 2162688);        // 8 B

  (void)hipMemsetAsync(totg, 0, 65544, stream);  // totg, tposg, scal

  prep_kernel<<<NN / 16, 256, 0, stream>>>(x, fb);
  fused128_kernel<<<dim3(16, 64), 256, 0, stream>>>(fb, pl, sl, totg, tposg);
  final1_k<<<NN / 256, 256, 0, stream>>>(totg, tposg, pl, sl, scal);
  final2_k<<<1, 1, 0, stream>>>(scal, (float*)d_out);
}